// Round 2
// baseline (584.202 us; speedup 1.0000x reference)
//
#include <hip/hip_runtime.h>

#define BATCH 8192
#define V 512
#define N1 513
#define KCH 16
#define NCHUNKS 32
#define RB 32            // rows per block -> grid 256
#define NT 1024          // 16 waves in ONE block -> 4 waves/SIMD guaranteed
#define PKS 520          // Phi row stride (bf16 elems)
#define SJP 772          // padded S row stride (dwords): col j at 12*(j>>3)+(j&7)

typedef __bf16 bf16_t;
typedef bf16_t bf16x8 __attribute__((ext_vector_type(8)));
typedef float f32x4 __attribute__((ext_vector_type(4)));
typedef float f32x2 __attribute__((ext_vector_type(2)));

// workspace: Mhi (fragment-linear triangular pack, mat=1 tiles PRE-NEGATED),
// Dv (fp32, pre-scaled by mat sign), Bv (fp32, pre-negated mat=1).
//   chunk cc in 1..31: nkb = ceil(cc/2) k-blocks of 32 (zero-pad past 16*cc);
//   base elems = 16384*floor(cc^2/4); elem = base + (kb*32 + t)*512 + lane*8 + jj
//   with t = 2*vl + mat, lane = c + 16*q, k = kb*32 + 8*q + jj.
// Dv: [cc][vl][512 j], j = 32*vlo + 16*mat + c. Bv: [cc][512 j].
#define EPP 4194304ull
#define DV_OFF (EPP * 2ull)
#define BV_OFF (DV_OFF + 1048576ull)

__device__ __forceinline__ f32x4 mfma16(bf16x8 a, bf16x8 b, f32x4 c) {
    return __builtin_amdgcn_mfma_f32_16x16x32_bf16(a, b, c, 0, 0, 0);
}

__device__ __forceinline__ float bcast_lane(float x, int l) {
    return __int_as_float(__builtin_amdgcn_readlane(__float_as_int(x), l));
}

__device__ __forceinline__ float dpp_xor1_max(float x) {
    const int xi = __float_as_int(x);
    // quad_perm [1,0,3,2] = 0xB1 -> swap xor-1 neighbours, no DS op
    const float o = __int_as_float(
        __builtin_amdgcn_update_dpp(xi, xi, 0xB1, 0xF, 0xF, false));
    return fmaxf(x, o);
}

// ---- unified repack: blocks 0..495 pack Mhi (LDS-staged so the pos/neg reads
// are coalesced 128B rows); 496..527 pack Dv/Bv (per-cc, LDS-transposed) ------
__global__ __launch_bounds__(256)
void repack_all(const float* __restrict__ pos, const float* __restrict__ neg,
                bf16_t* __restrict__ Mhi, float* __restrict__ Dv,
                float* __restrict__ Bv)
{
    __shared__ float sb[2 * 256 * 33];   // 67,584 B; Dv path aliases stride-17
    const int bx = blockIdx.x;
    if (bx < 496) {
        const int cc  = (bx >> 4) + 1;       // 1..31
        const int kb  = bx & 15;
        const int nkb = (cc + 1) >> 1;
        if (kb >= nkb) return;
        const int klen = 16 * cc;
        // stage tile rows [cc*256,+256) x cols [kb*32,+32), coalesced, signed,
        // zero-padded past klen
        for (int idx = threadIdx.x; idx < 8192; idx += 256) {
            const int r = idx >> 5, k32 = idx & 31;
            const int k = kb * 32 + k32;
            const size_t row = (size_t)cc * 256 + r;
            float xp = 0.0f, xn = 0.0f;
            if (k < klen) {
                xp = pos[row * N1 + k];
                xn = -neg[row * N1 + k];     // pre-negate mat=1
            }
            sb[r * 33 + k32]            = xp;
            sb[256 * 33 + r * 33 + k32] = xn;
        }
        __syncthreads();
        const size_t base = 16384ull * (size_t)((cc * cc) / 4) + (size_t)kb * 16384ull;
        for (int e = threadIdx.x; e < 16384; e += 256) {
            const int t = e >> 9, s = (e >> 3) & 63, jj = e & 7;
            const int c = s & 15, q = s >> 4;
            const int vloc = t >> 1, m = t & 1;
            const int r = vloc * 16 + c;
            const int kl = 8 * q + jj;
            Mhi[base + e] = (bf16_t)sb[m * 256 * 33 + r * 33 + kl];
        }
    } else {
        const int cc = bx - 496;             // 0..31, one block per chunk
        float* bufP = sb;                    // stride-17 views
        float* bufN = sb + 256 * 17;
        // stage rows [cc*256, cc*256+256) cols [cc*16, cc*16+16), coalesced
        for (int idx = threadIdx.x; idx < 4096; idx += 256) {
            const int r = idx >> 4, kk = idx & 15;
            const size_t row = (size_t)(cc * 256 + r);
            bufP[r * 17 + kk] = pos[row * N1 + cc * 16 + kk];
            bufN[r * 17 + kk] = neg[row * N1 + cc * 16 + kk];
        }
        __syncthreads();
        // Dv: [vl][512 j], writes coalesced, reads from LDS transpose
        for (int idx = threadIdx.x; idx < 8192; idx += 256) {
            const int vl = idx >> 9, j = idx & 511;
            const int vlo = j >> 5, c = j & 15;
            const int m = (j >> 4) & 1;
            const float x = (m ? bufN : bufP)[(vlo * 16 + c) * 17 + vl];
            Dv[(size_t)cc * 8192 + idx] = m ? -x : x;
        }
        // Bv: 512 per chunk (bias column), tiny scattered read is fine
        for (int j = threadIdx.x; j < 512; j += 256) {
            const int vlo = j >> 5, c = j & 15;
            const int m = (j >> 4) & 1;
            const float* src = m ? neg : pos;
            const float x = src[(size_t)(cc * 256 + vlo * 16 + c) * N1 + V];
            Bv[(size_t)cc * 512 + j] = m ? -x : x;
        }
    }
}

// ---- fused main kernel: 32 rows, 16 waves, grid 256 ----------------------------
// Wave w: GEMM j-tiles t = 2w..2w+1 (both 16-row halves, acc[2][2]); chain owns
// rows 2w..2w+1. Per chunk: dump acc -> S, barrier, 16-step barrier-free in-wave
// chain interleaving chunk cc+1's bulk GEMM k-blocks, barrier, final k-block.
// mat=1 values live negated end-to-end: every reduce is max, upper = -red.
// R2: explicit 1-step software pipeline on dv/fa/fb — all prefetched data is
// step-invariant (Dv/Mhi constant; in-loop fa reads Phi cols k < 16cc, strictly
// older than any chain write). Forces the 128-VGPR budget from (NT,4) to be
// used for load cover instead of sinking loads next to uses.
__global__ __launch_bounds__(NT, 4)
void shield_fused(const float* __restrict__ preds,
                  const bf16_t* __restrict__ Mhi,
                  const float* __restrict__ Dv, const float* __restrict__ Bv,
                  float* __restrict__ out)
{
    __shared__ bf16_t Phi[RB * PKS];   // 33,280 B
    __shared__ float  S[RB * SJP];     // 98,816 B  (total 132,096 -> 1 block/CU)

    const int tid  = threadIdx.x;
    const int b0   = blockIdx.x * RB;
    const int lane = tid & 63;
    const int w    = tid >> 6;          // 0..15
    const int cq   = lane & 15;
    const int q    = lane >> 4;
    const int rp0  = w * 2;             // chain rows 2w, 2w+1

    // ---- load preds -> Phi ----
    {
        const int r = tid >> 5, seg = tid & 31;
        const float* prow = preds + (size_t)(b0 + r) * V + seg * 16;
        #pragma unroll
        for (int k = 0; k < 16; k += 4) {
            const float4 p4 = *(const float4*)(prow + k);
            const int n = seg * 16 + k;
            Phi[r * PKS + n + 0] = (bf16_t)p4.x;
            Phi[r * PKS + n + 1] = (bf16_t)p4.y;
            Phi[r * PKS + n + 2] = (bf16_t)p4.z;
            Phi[r * PKS + n + 3] = (bf16_t)p4.w;
        }
    }

    int tJ[2], sct[2];
    #pragma unroll
    for (int tt = 0; tt < 2; ++tt) {
        tJ[tt]  = ((2 * w + tt) << 4) + cq;
        sct[tt] = 12 * (tJ[tt] >> 3) + (tJ[tt] & 7);   // padded S column
    }
    const int aoff0 = cq * PKS + 8 * q;
    const int aoff1 = (16 + cq) * PKS + 8 * q;

    // acc(0) = bias(0)
    f32x4 acc[2][2];
    #pragma unroll
    for (int tt = 0; tt < 2; ++tt) {
        const float b = Bv[tJ[tt]];
        acc[0][tt] = f32x4{b, b, b, b};
        acc[1][tt] = f32x4{b, b, b, b};
    }

    #pragma unroll 1
    for (int cc = 0; cc < NCHUNKS; ++cc) {
        const int v0 = cc * 16;
        const int  ccn  = cc + 1;
        const bool hasN = ccn < NCHUNKS;
        const int  nkbN = hasN ? ((ccn + 1) >> 1) : 0;
        const bf16_t* phN = Mhi + 16384ull * (size_t)((ccn * ccn) / 4)
                          + (size_t)lane * 8 + (size_t)(2 * w) * 512;

        // ---- dump acc(cc) -> S (padded columns) ----
        #pragma unroll
        for (int tt = 0; tt < 2; ++tt)
            #pragma unroll
            for (int reg = 0; reg < 4; ++reg) {
                S[(4 * q + reg) * SJP + sct[tt]]      = acc[0][tt][reg];
                S[(16 + 4 * q + reg) * SJP + sct[tt]] = acc[1][tt][reg];
            }
        __syncthreads();   // (A) S ready; prior Phi writes visible

        // ---- load s2: lane owns j = 8*lane..8*lane+7, rows 2w / 2w+1 ----
        // padded layout: group g at dword 12*g -> 8 consecutive lanes cover all
        // 32 banks exactly once per b128 (optimal 8 phases)
        f32x2 s2[8];
        {
            const float* sp = &S[rp0 * SJP + 12 * lane];
            const float4 a0 = *(const float4*)(sp);
            const float4 a1 = *(const float4*)(sp + 4);
            const float4 c0 = *(const float4*)(sp + SJP);
            const float4 c1 = *(const float4*)(sp + SJP + 4);
            s2[0] = f32x2{a0.x, c0.x}; s2[1] = f32x2{a0.y, c0.y};
            s2[2] = f32x2{a0.z, c0.z}; s2[3] = f32x2{a0.w, c0.w};
            s2[4] = f32x2{a1.x, c1.x}; s2[5] = f32x2{a1.y, c1.y};
            s2[6] = f32x2{a1.z, c1.z}; s2[7] = f32x2{a1.w, c1.w};
        }

        // ---- prefetch this chunk's po values (cols v0..v0+15, both rows) ----
        const bf16x8 poA0 = *(const bf16x8*)(Phi + rp0 * PKS + v0);
        const bf16x8 poA1 = *(const bf16x8*)(Phi + rp0 * PKS + v0 + 8);
        const bf16x8 poB0 = *(const bf16x8*)(Phi + (rp0 + 1) * PKS + v0);
        const bf16x8 poB1 = *(const bf16x8*)(Phi + (rp0 + 1) * PKS + v0 + 8);

        // ---- init acc(ccn) with bias ----
        if (hasN) {
            #pragma unroll
            for (int tt = 0; tt < 2; ++tt) {
                const float b = Bv[(ccn << 9) + tJ[tt]];
                acc[0][tt] = f32x4{b, b, b, b};
                acc[1][tt] = f32x4{b, b, b, b};
            }
        }

        // ---- pipeline prologue: loads for step 0 ----
        float4 dn0, dn1;
        {
            const float* dp = Dv + ((size_t)v0 << 9) + 8 * lane;
            dn0 = *(const float4*)(dp);
            dn1 = *(const float4*)(dp + 4);
        }
        bf16x8 fan0, fan1, fbn0, fbn1;
        if (hasN && 0 < nkbN - 1) {
            fan0 = *(const bf16x8*)(Phi + aoff0);
            fan1 = *(const bf16x8*)(Phi + aoff1);
            fbn0 = *(const bf16x8*)(phN);
            fbn1 = *(const bf16x8*)(phN + 512);
        }

        // ---- 16-step serial chain + interleaved bulk GEMM of chunk ccn ----
        #pragma unroll
        for (int vl = 0; vl < KCH; ++vl) {
            const int vcur = v0 + vl;
            const bool doKb  = hasN && (vl < nkbN - 1);
            const bool doKbN = hasN && (vl + 1 < nkbN - 1);

            // consume this step's prefetched regs (SSA renames, free)
            const float4 dc0 = dn0, dc1 = dn1;
            const bf16x8 fa0 = fan0, fa1 = fan1, fb0 = fbn0, fb1 = fbn1;

            // issue NEXT step's loads now: a full chain-step of latency cover
            if (vl + 1 < KCH) {
                const float* dp = Dv + ((size_t)(vcur + 1) << 9) + 8 * lane;
                dn0 = *(const float4*)(dp);
                dn1 = *(const float4*)(dp + 4);
            }
            if (doKbN) {
                const int k0 = (vl + 1) * 32;
                fan0 = *(const bf16x8*)(Phi + aoff0 + k0);
                fan1 = *(const bf16x8*)(Phi + aoff1 + k0);
                const bf16_t* pb = phN + (size_t)k0 * 512;
                fbn0 = *(const bf16x8*)(pb);
                fbn1 = *(const bf16x8*)(pb + 512);
            }

            const float po_[2] = {
                (float)(vl < 8 ? poA0[vl & 7] : poA1[vl & 7]),
                (float)(vl < 8 ? poB0[vl & 7] : poB1[vl & 7])
            };

            // in-lane reduce 8 -> 1 per row (max3-fusable), xor-1 merge via DPP
            float red[2];
            #pragma unroll
            for (int r = 0; r < 2; ++r) {
                const float m0 = fmaxf(fmaxf(s2[0][r], s2[1][r]), s2[2][r]);
                const float m1 = fmaxf(fmaxf(s2[3][r], s2[4][r]), s2[5][r]);
                const float m2 = fmaxf(s2[6][r], s2[7][r]);
                const float mxr = fmaxf(fmaxf(m0, m1), m2);
                red[r] = dpp_xor1_max(mxr);
            }
            // broadcast from compile-time lanes via v_readlane (no DS op)
            float pc[2];
            #pragma unroll
            for (int r = 0; r < 2; ++r) {
                const float lw  = bcast_lane(red[r], 4 * vl);       // lower
                const float nup = bcast_lane(red[r], 4 * vl + 2);   // -upper
                pc[r] = fminf(fmaxf(po_[r], lw), -nup);
            }
            if (lane == 4 * vl) {
                Phi[rp0 * PKS + vcur]       = (bf16_t)pc[0];
                Phi[(rp0 + 1) * PKS + vcur] = (bf16_t)pc[1];
            }
            // rank-1 update (packed fp32 fma; Dv pre-scaled so no sign mul)
            const f32x2 pcv = {pc[0], pc[1]};
            {
                const float dvv[8] = {dc0.x, dc0.y, dc0.z, dc0.w,
                                      dc1.x, dc1.y, dc1.z, dc1.w};
                #pragma unroll
                for (int jj = 0; jj < 8; ++jj) {
                    const f32x2 dsp = {dvv[jj], dvv[jj]};
                    s2[jj] = __builtin_elementwise_fma(dsp, pcv, s2[jj]);
                }
            }

            if (doKb) {
                acc[0][0] = mfma16(fa0, fb0, acc[0][0]);
                acc[1][0] = mfma16(fa1, fb0, acc[1][0]);
                acc[0][1] = mfma16(fa0, fb1, acc[0][1]);
                acc[1][1] = mfma16(fa1, fb1, acc[1][1]);
            }
        }

        __syncthreads();   // (D) fresh Phi columns visible; S safe to reuse

        // ---- final k-block of chunk ccn (zero-padded B -> exact no-ops) ----
        if (hasN) {
            const int k0 = (nkbN - 1) * 32;
            const bf16x8 fa0 = *(const bf16x8*)(Phi + aoff0 + k0);
            const bf16x8 fa1 = *(const bf16x8*)(Phi + aoff1 + k0);
            const bf16_t* pb = phN + (size_t)k0 * 512;
            const bf16x8 fb0 = *(const bf16x8*)(pb);
            const bf16x8 fb1 = *(const bf16x8*)(pb + 512);
            acc[0][0] = mfma16(fa0, fb0, acc[0][0]);
            acc[1][0] = mfma16(fa1, fb0, acc[1][0]);
            acc[0][1] = mfma16(fa0, fb1, acc[0][1]);
            acc[1][1] = mfma16(fa1, fb1, acc[1][1]);
        }
    }

    // ---- epilogue ----
    {
        const int r = tid >> 5, seg = tid & 31;
        float* orow = out + (size_t)(b0 + r) * V + seg * 16;
        #pragma unroll
        for (int k = 0; k < 16; k += 4) {
            const int n = seg * 16 + k;
            float4 o;
            o.x = (float)Phi[r * PKS + n + 0];
            o.y = (float)Phi[r * PKS + n + 1];
            o.z = (float)Phi[r * PKS + n + 2];
            o.w = (float)Phi[r * PKS + n + 3];
            *(float4*)(orow + k) = o;
        }
    }
}

extern "C" void kernel_launch(void* const* d_in, const int* in_sizes, int n_in,
                              void* d_out, int out_size, void* d_ws, size_t ws_size,
                              hipStream_t stream) {
    const float* preds = (const float*)d_in[0];
    const float* pos   = (const float*)d_in[1];
    const float* neg   = (const float*)d_in[2];
    float* o = (float*)d_out;
    char* base = (char*)d_ws;
    bf16_t* Mhi = (bf16_t*)base;
    float*  Dv  = (float*)(base + DV_OFF);
    float*  Bv  = (float*)(base + BV_OFF);
    repack_all<<<dim3(528), 256, 0, stream>>>(pos, neg, Mhi, Dv, Bv);
    shield_fused<<<dim3(BATCH / RB), NT, 0, stream>>>(preds, Mhi, Dv, Bv, o);
}

// Round 3
// 417.004 us; speedup vs baseline: 1.4009x; 1.4009x over previous
//
#include <hip/hip_runtime.h>

#define BATCH 8192
#define V 512
#define N1 513
#define KCH 16
#define NCHUNKS 32
#define RB 32            // rows per block -> grid 256
#define NT 1024          // 16 waves in ONE block -> 4 waves/SIMD guaranteed
#define PKS 520          // Phi row stride (bf16 elems)
#define SJP 772          // padded S row stride (dwords): col j at 12*(j>>3)+(j&7)

typedef __bf16 bf16_t;
typedef bf16_t bf16x8 __attribute__((ext_vector_type(8)));
typedef float f32x4 __attribute__((ext_vector_type(4)));
typedef float f32x2 __attribute__((ext_vector_type(2)));

// workspace: Mhi (fragment-linear triangular pack, mat=1 tiles PRE-NEGATED),
// Dv (fp32, pre-scaled by mat sign), Bv (fp32, pre-negated mat=1).
//   chunk cc in 1..31: nkb = ceil(cc/2) k-blocks of 32 (zero-pad past 16*cc);
//   base elems = 16384*floor(cc^2/4); elem = base + (kb*32 + t)*512 + lane*8 + jj
//   with t = 2*vl + mat, lane = c + 16*q, k = kb*32 + 8*q + jj.
// Dv: [cc][vl][512 j], j = 32*vlo + 16*mat + c. Bv: [cc][512 j].
#define EPP 4194304ull
#define DV_OFF (EPP * 2ull)
#define BV_OFF (DV_OFF + 1048576ull)

__device__ __forceinline__ f32x4 mfma16(bf16x8 a, bf16x8 b, f32x4 c) {
    return __builtin_amdgcn_mfma_f32_16x16x32_bf16(a, b, c, 0, 0, 0);
}

__device__ __forceinline__ float bcast_lane(float x, int l) {
    return __int_as_float(__builtin_amdgcn_readlane(__float_as_int(x), l));
}

__device__ __forceinline__ float dpp_xor1_max(float x) {
    const int xi = __float_as_int(x);
    // quad_perm [1,0,3,2] = 0xB1 -> swap xor-1 neighbours, no DS op
    const float o = __int_as_float(
        __builtin_amdgcn_update_dpp(xi, xi, 0xB1, 0xF, 0xF, false));
    return fmaxf(x, o);
}

// ---- unified repack: blocks 0..495 pack Mhi (LDS-staged so the pos/neg reads
// are coalesced 128B rows); 496..527 pack Dv/Bv (per-cc, LDS-transposed) ------
__global__ __launch_bounds__(256)
void repack_all(const float* __restrict__ pos, const float* __restrict__ neg,
                bf16_t* __restrict__ Mhi, float* __restrict__ Dv,
                float* __restrict__ Bv)
{
    __shared__ float sb[2 * 256 * 33];   // 67,584 B; Dv path aliases stride-17
    const int bx = blockIdx.x;
    if (bx < 496) {
        const int cc  = (bx >> 4) + 1;       // 1..31
        const int kb  = bx & 15;
        const int nkb = (cc + 1) >> 1;
        if (kb >= nkb) return;
        const int klen = 16 * cc;
        // stage tile rows [cc*256,+256) x cols [kb*32,+32), coalesced, signed,
        // zero-padded past klen
        for (int idx = threadIdx.x; idx < 8192; idx += 256) {
            const int r = idx >> 5, k32 = idx & 31;
            const int k = kb * 32 + k32;
            const size_t row = (size_t)cc * 256 + r;
            float xp = 0.0f, xn = 0.0f;
            if (k < klen) {
                xp = pos[row * N1 + k];
                xn = -neg[row * N1 + k];     // pre-negate mat=1
            }
            sb[r * 33 + k32]            = xp;
            sb[256 * 33 + r * 33 + k32] = xn;
        }
        __syncthreads();
        const size_t base = 16384ull * (size_t)((cc * cc) / 4) + (size_t)kb * 16384ull;
        for (int e = threadIdx.x; e < 16384; e += 256) {
            const int t = e >> 9, s = (e >> 3) & 63, jj = e & 7;
            const int c = s & 15, q = s >> 4;
            const int vloc = t >> 1, m = t & 1;
            const int r = vloc * 16 + c;
            const int kl = 8 * q + jj;
            Mhi[base + e] = (bf16_t)sb[m * 256 * 33 + r * 33 + kl];
        }
    } else {
        const int cc = bx - 496;             // 0..31, one block per chunk
        float* bufP = sb;                    // stride-17 views
        float* bufN = sb + 256 * 17;
        // stage rows [cc*256, cc*256+256) cols [cc*16, cc*16+16), coalesced
        for (int idx = threadIdx.x; idx < 4096; idx += 256) {
            const int r = idx >> 4, kk = idx & 15;
            const size_t row = (size_t)(cc * 256 + r);
            bufP[r * 17 + kk] = pos[row * N1 + cc * 16 + kk];
            bufN[r * 17 + kk] = neg[row * N1 + cc * 16 + kk];
        }
        __syncthreads();
        // Dv: [vl][512 j], writes coalesced, reads from LDS transpose
        for (int idx = threadIdx.x; idx < 8192; idx += 256) {
            const int vl = idx >> 9, j = idx & 511;
            const int vlo = j >> 5, c = j & 15;
            const int m = (j >> 4) & 1;
            const float x = (m ? bufN : bufP)[(vlo * 16 + c) * 17 + vl];
            Dv[(size_t)cc * 8192 + idx] = m ? -x : x;
        }
        // Bv: 512 per chunk (bias column), tiny scattered read is fine
        for (int j = threadIdx.x; j < 512; j += 256) {
            const int vlo = j >> 5, c = j & 15;
            const int m = (j >> 4) & 1;
            const float* src = m ? neg : pos;
            const float x = src[(size_t)(cc * 256 + vlo * 16 + c) * N1 + V];
            Bv[(size_t)cc * 512 + j] = m ? -x : x;
        }
    }
}

// ---- fused main kernel: 32 rows, 16 waves, grid 256 ----------------------------
// Wave w: GEMM j-tiles t = 2w..2w+1 (both 16-row halves, acc[2][2]); chain owns
// rows 2w..2w+1. Per chunk: dump acc -> S, barrier, 16-step barrier-free in-wave
// chain interleaving chunk cc+1's bulk GEMM k-blocks, barrier, final k-block.
// mat=1 values live negated end-to-end: every reduce is max, upper = -red.
// R3: fb-ONLY software pipeline (R2's full dv/fa/fb pipeline exceeded the
// 128-VGPR cap of a 1024-thread block and spilled: WRITE_SIZE 18->685 MB).
// fb (global Mhi, L2/L3 ~200-400cy) is the largest exposed latency; one-step
// prefetch costs only +16 VGPRs in the live window. fa (LDS) is issued at the
// top of the step (~100cy cover, no cross-step pressure). dv stays in-step
// (L1/L2-hot, smallest stall). Final k-block's fb is prefetched during the
// chain (Mhi is constant -> race-free), with in-place fallback when nkbN==1.
__global__ __launch_bounds__(NT, 4)
void shield_fused(const float* __restrict__ preds,
                  const bf16_t* __restrict__ Mhi,
                  const float* __restrict__ Dv, const float* __restrict__ Bv,
                  float* __restrict__ out)
{
    __shared__ bf16_t Phi[RB * PKS];   // 33,280 B
    __shared__ float  S[RB * SJP];     // 98,816 B  (total 132,096 -> 1 block/CU)

    const int tid  = threadIdx.x;
    const int b0   = blockIdx.x * RB;
    const int lane = tid & 63;
    const int w    = tid >> 6;          // 0..15
    const int cq   = lane & 15;
    const int q    = lane >> 4;
    const int rp0  = w * 2;             // chain rows 2w, 2w+1

    // ---- load preds -> Phi ----
    {
        const int r = tid >> 5, seg = tid & 31;
        const float* prow = preds + (size_t)(b0 + r) * V + seg * 16;
        #pragma unroll
        for (int k = 0; k < 16; k += 4) {
            const float4 p4 = *(const float4*)(prow + k);
            const int n = seg * 16 + k;
            Phi[r * PKS + n + 0] = (bf16_t)p4.x;
            Phi[r * PKS + n + 1] = (bf16_t)p4.y;
            Phi[r * PKS + n + 2] = (bf16_t)p4.z;
            Phi[r * PKS + n + 3] = (bf16_t)p4.w;
        }
    }

    int tJ[2], sct[2];
    #pragma unroll
    for (int tt = 0; tt < 2; ++tt) {
        tJ[tt]  = ((2 * w + tt) << 4) + cq;
        sct[tt] = 12 * (tJ[tt] >> 3) + (tJ[tt] & 7);   // padded S column
    }
    const int aoff0 = cq * PKS + 8 * q;
    const int aoff1 = (16 + cq) * PKS + 8 * q;

    // acc(0) = bias(0)
    f32x4 acc[2][2];
    #pragma unroll
    for (int tt = 0; tt < 2; ++tt) {
        const float b = Bv[tJ[tt]];
        acc[0][tt] = f32x4{b, b, b, b};
        acc[1][tt] = f32x4{b, b, b, b};
    }

    #pragma unroll 1
    for (int cc = 0; cc < NCHUNKS; ++cc) {
        const int v0 = cc * 16;
        const int  ccn  = cc + 1;
        const bool hasN = ccn < NCHUNKS;
        const int  nkbN = hasN ? ((ccn + 1) >> 1) : 0;
        const bf16_t* phN = Mhi + 16384ull * (size_t)((ccn * ccn) / 4)
                          + (size_t)lane * 8 + (size_t)(2 * w) * 512;

        // ---- dump acc(cc) -> S (padded columns) ----
        #pragma unroll
        for (int tt = 0; tt < 2; ++tt)
            #pragma unroll
            for (int reg = 0; reg < 4; ++reg) {
                S[(4 * q + reg) * SJP + sct[tt]]      = acc[0][tt][reg];
                S[(16 + 4 * q + reg) * SJP + sct[tt]] = acc[1][tt][reg];
            }
        __syncthreads();   // (A) S ready; prior Phi writes visible

        // ---- load s2: lane owns j = 8*lane..8*lane+7, rows 2w / 2w+1 ----
        // padded layout: group g at dword 12*g -> 8 consecutive lanes cover all
        // 32 banks exactly once per b128 (optimal 8 phases)
        f32x2 s2[8];
        {
            const float* sp = &S[rp0 * SJP + 12 * lane];
            const float4 a0 = *(const float4*)(sp);
            const float4 a1 = *(const float4*)(sp + 4);
            const float4 c0 = *(const float4*)(sp + SJP);
            const float4 c1 = *(const float4*)(sp + SJP + 4);
            s2[0] = f32x2{a0.x, c0.x}; s2[1] = f32x2{a0.y, c0.y};
            s2[2] = f32x2{a0.z, c0.z}; s2[3] = f32x2{a0.w, c0.w};
            s2[4] = f32x2{a1.x, c1.x}; s2[5] = f32x2{a1.y, c1.y};
            s2[6] = f32x2{a1.z, c1.z}; s2[7] = f32x2{a1.w, c1.w};
        }

        // ---- prefetch this chunk's po values (cols v0..v0+15, both rows) ----
        const bf16x8 poA0 = *(const bf16x8*)(Phi + rp0 * PKS + v0);
        const bf16x8 poA1 = *(const bf16x8*)(Phi + rp0 * PKS + v0 + 8);
        const bf16x8 poB0 = *(const bf16x8*)(Phi + (rp0 + 1) * PKS + v0);
        const bf16x8 poB1 = *(const bf16x8*)(Phi + (rp0 + 1) * PKS + v0 + 8);

        // ---- init acc(ccn) with bias ----
        if (hasN) {
            #pragma unroll
            for (int tt = 0; tt < 2; ++tt) {
                const float b = Bv[(ccn << 9) + tJ[tt]];
                acc[0][tt] = f32x4{b, b, b, b};
                acc[1][tt] = f32x4{b, b, b, b};
            }
        }

        // ---- fb pipeline prologue: k-block 0 of chunk ccn ----
        bf16x8 fbn0, fbn1;
        if (hasN && nkbN > 1) {
            fbn0 = *(const bf16x8*)(phN);
            fbn1 = *(const bf16x8*)(phN + 512);
        }

        // ---- 16-step serial chain + interleaved bulk GEMM of chunk ccn ----
        #pragma unroll
        for (int vl = 0; vl < KCH; ++vl) {
            const int vcur = v0 + vl;
            const bool doKb  = hasN && (vl < nkbN - 1);
            const bool doKbN = hasN && (vl + 1 < nkbN - 1);
            const bool doFin = hasN && (vl + 1 == nkbN - 1);  // final kb's fb

            // consume this step's fb; issue next step's (or the final
            // k-block's) fb NOW -> a full chain-step of global-latency cover.
            // Mhi is constant, so this never races the chain's Phi writes.
            const bf16x8 fb0 = fbn0, fb1 = fbn1;
            if (doKbN || doFin) {
                const int k0 = (vl + 1) * 32;
                const bf16_t* pb = phN + (size_t)k0 * 512;
                fbn0 = *(const bf16x8*)(pb);
                fbn1 = *(const bf16x8*)(pb + 512);
            }

            // fa (LDS) issued at step top: ~100cy of in-step cover, and reads
            // only Phi cols k < 16*cc -- strictly older than any chain write
            bf16x8 fa0, fa1;
            if (doKb) {
                const int k0 = vl * 32;
                fa0 = *(const bf16x8*)(Phi + aoff0 + k0);
                fa1 = *(const bf16x8*)(Phi + aoff1 + k0);
            }

            // this step's dv (global, L1/L2-hot); consumed post-reduce
            float dv[8];
            {
                const float* dp = Dv + ((size_t)vcur << 9) + 8 * lane;
                const float4 d0 = *(const float4*)(dp);
                const float4 d1 = *(const float4*)(dp + 4);
                dv[0]=d0.x; dv[1]=d0.y; dv[2]=d0.z; dv[3]=d0.w;
                dv[4]=d1.x; dv[5]=d1.y; dv[6]=d1.z; dv[7]=d1.w;
            }
            const float po_[2] = {
                (float)(vl < 8 ? poA0[vl & 7] : poA1[vl & 7]),
                (float)(vl < 8 ? poB0[vl & 7] : poB1[vl & 7])
            };

            // in-lane reduce 8 -> 1 per row (max3-fusable), xor-1 merge via DPP
            float red[2];
            #pragma unroll
            for (int r = 0; r < 2; ++r) {
                const float m0 = fmaxf(fmaxf(s2[0][r], s2[1][r]), s2[2][r]);
                const float m1 = fmaxf(fmaxf(s2[3][r], s2[4][r]), s2[5][r]);
                const float m2 = fmaxf(s2[6][r], s2[7][r]);
                const float mxr = fmaxf(fmaxf(m0, m1), m2);
                red[r] = dpp_xor1_max(mxr);
            }
            // broadcast from compile-time lanes via v_readlane (no DS op)
            float pc[2];
            #pragma unroll
            for (int r = 0; r < 2; ++r) {
                const float lw  = bcast_lane(red[r], 4 * vl);       // lower
                const float nup = bcast_lane(red[r], 4 * vl + 2);   // -upper
                pc[r] = fminf(fmaxf(po_[r], lw), -nup);
            }
            if (lane == 4 * vl) {
                Phi[rp0 * PKS + vcur]       = (bf16_t)pc[0];
                Phi[(rp0 + 1) * PKS + vcur] = (bf16_t)pc[1];
            }
            // rank-1 update (packed fp32 fma; Dv pre-scaled so no sign mul)
            const f32x2 pcv = {pc[0], pc[1]};
            #pragma unroll
            for (int jj = 0; jj < 8; ++jj) {
                const f32x2 dsp = {dv[jj], dv[jj]};
                s2[jj] = __builtin_elementwise_fma(dsp, pcv, s2[jj]);
            }

            if (doKb) {
                acc[0][0] = mfma16(fa0, fb0, acc[0][0]);
                acc[1][0] = mfma16(fa1, fb0, acc[1][0]);
                acc[0][1] = mfma16(fa0, fb1, acc[0][1]);
                acc[1][1] = mfma16(fa1, fb1, acc[1][1]);
            }
        }

        __syncthreads();   // (D) fresh Phi columns visible; S safe to reuse

        // ---- final k-block of chunk ccn (zero-padded B -> exact no-ops) ----
        // fb was prefetched during the chain (doFin) except when nkbN==1.
        if (hasN) {
            const int k0 = (nkbN - 1) * 32;
            bf16x8 fb0f = fbn0, fb1f = fbn1;
            if (nkbN == 1) {
                const bf16_t* pb = phN + (size_t)k0 * 512;
                fb0f = *(const bf16x8*)(pb);
                fb1f = *(const bf16x8*)(pb + 512);
            }
            const bf16x8 fa0 = *(const bf16x8*)(Phi + aoff0 + k0);
            const bf16x8 fa1 = *(const bf16x8*)(Phi + aoff1 + k0);
            acc[0][0] = mfma16(fa0, fb0f, acc[0][0]);
            acc[1][0] = mfma16(fa1, fb0f, acc[1][0]);
            acc[0][1] = mfma16(fa0, fb1f, acc[0][1]);
            acc[1][1] = mfma16(fa1, fb1f, acc[1][1]);
        }
    }

    // ---- epilogue ----
    {
        const int r = tid >> 5, seg = tid & 31;
        float* orow = out + (size_t)(b0 + r) * V + seg * 16;
        #pragma unroll
        for (int k = 0; k < 16; k += 4) {
            const int n = seg * 16 + k;
            float4 o;
            o.x = (float)Phi[r * PKS + n + 0];
            o.y = (float)Phi[r * PKS + n + 1];
            o.z = (float)Phi[r * PKS + n + 2];
            o.w = (float)Phi[r * PKS + n + 3];
            *(float4*)(orow + k) = o;
        }
    }
}

extern "C" void kernel_launch(void* const* d_in, const int* in_sizes, int n_in,
                              void* d_out, int out_size, void* d_ws, size_t ws_size,
                              hipStream_t stream) {
    const float* preds = (const float*)d_in[0];
    const float* pos   = (const float*)d_in[1];
    const float* neg   = (const float*)d_in[2];
    float* o = (float*)d_out;
    char* base = (char*)d_ws;
    bf16_t* Mhi = (bf16_t*)base;
    float*  Dv  = (float*)(base + DV_OFF);
    float*  Bv  = (float*)(base + BV_OFF);
    repack_all<<<dim3(528), 256, 0, stream>>>(pos, neg, Mhi, Dv, Bv);
    shield_fused<<<dim3(BATCH / RB), NT, 0, stream>>>(preds, Mhi, Dv, Bv, o);
}

// Round 4
// 403.176 us; speedup vs baseline: 1.4490x; 1.0343x over previous
//
#include <hip/hip_runtime.h>

#define BATCH 8192
#define V 512
#define N1 513
#define KCH 16
#define NCHUNKS 32
#define RB 32            // rows per block -> grid 256
#define NT 1024          // 16 waves in ONE block -> 4 waves/SIMD guaranteed
#define PKS 520          // Phi row stride (bf16 elems)
#define SJP 772          // padded S row stride (dwords): col j at 12*(j>>3)+(j&7)

typedef __bf16 bf16_t;
typedef bf16_t bf16x8 __attribute__((ext_vector_type(8)));
typedef float f32x4 __attribute__((ext_vector_type(4)));
typedef float f32x2 __attribute__((ext_vector_type(2)));

// workspace: Mhi (fragment-linear triangular pack, mat=1 tiles PRE-NEGATED),
// Dv (fp32, pre-scaled by mat sign), Bv (fp32, pre-negated mat=1).
//   chunk cc in 1..31: nkb = ceil(cc/2) k-blocks of 32 (zero-pad past 16*cc);
//   base elems = 16384*floor(cc^2/4); elem = base + (kb*32 + t)*512 + lane*8 + jj
//   with t = 2*vl + mat, lane = c + 16*q, k = kb*32 + 8*q + jj.
// Dv: [cc][vl][512 j], j = 32*vlo + 16*mat + c. Bv: [cc][512 j].
#define EPP 4194304ull
#define DV_OFF (EPP * 2ull)
#define BV_OFF (DV_OFF + 1048576ull)

__device__ __forceinline__ f32x4 mfma16(bf16x8 a, bf16x8 b, f32x4 c) {
    return __builtin_amdgcn_mfma_f32_16x16x32_bf16(a, b, c, 0, 0, 0);
}

__device__ __forceinline__ float bcast_lane(float x, int l) {
    return __int_as_float(__builtin_amdgcn_readlane(__float_as_int(x), l));
}

__device__ __forceinline__ float dpp_xor1_max(float x) {
    const int xi = __float_as_int(x);
    // quad_perm [1,0,3,2] = 0xB1 -> swap xor-1 neighbours, no DS op
    const float o = __int_as_float(
        __builtin_amdgcn_update_dpp(xi, xi, 0xB1, 0xF, 0xF, false));
    return fmaxf(x, o);
}

// ---- unified repack: blocks 0..495 pack Mhi (LDS-staged so the pos/neg reads
// are coalesced 128B rows); 496..527 pack Dv/Bv (per-cc, LDS-transposed) ------
__global__ __launch_bounds__(256)
void repack_all(const float* __restrict__ pos, const float* __restrict__ neg,
                bf16_t* __restrict__ Mhi, float* __restrict__ Dv,
                float* __restrict__ Bv)
{
    __shared__ float sb[2 * 256 * 33];   // 67,584 B; Dv path aliases stride-17
    const int bx = blockIdx.x;
    if (bx < 496) {
        const int cc  = (bx >> 4) + 1;       // 1..31
        const int kb  = bx & 15;
        const int nkb = (cc + 1) >> 1;
        if (kb >= nkb) return;
        const int klen = 16 * cc;
        // stage tile rows [cc*256,+256) x cols [kb*32,+32), coalesced, signed,
        // zero-padded past klen
        for (int idx = threadIdx.x; idx < 8192; idx += 256) {
            const int r = idx >> 5, k32 = idx & 31;
            const int k = kb * 32 + k32;
            const size_t row = (size_t)cc * 256 + r;
            float xp = 0.0f, xn = 0.0f;
            if (k < klen) {
                xp = pos[row * N1 + k];
                xn = -neg[row * N1 + k];     // pre-negate mat=1
            }
            sb[r * 33 + k32]            = xp;
            sb[256 * 33 + r * 33 + k32] = xn;
        }
        __syncthreads();
        const size_t base = 16384ull * (size_t)((cc * cc) / 4) + (size_t)kb * 16384ull;
        for (int e = threadIdx.x; e < 16384; e += 256) {
            const int t = e >> 9, s = (e >> 3) & 63, jj = e & 7;
            const int c = s & 15, q = s >> 4;
            const int vloc = t >> 1, m = t & 1;
            const int r = vloc * 16 + c;
            const int kl = 8 * q + jj;
            Mhi[base + e] = (bf16_t)sb[m * 256 * 33 + r * 33 + kl];
        }
    } else {
        const int cc = bx - 496;             // 0..31, one block per chunk
        float* bufP = sb;                    // stride-17 views
        float* bufN = sb + 256 * 17;
        // stage rows [cc*256, cc*256+256) cols [cc*16, cc*16+16), coalesced
        for (int idx = threadIdx.x; idx < 4096; idx += 256) {
            const int r = idx >> 4, kk = idx & 15;
            const size_t row = (size_t)(cc * 256 + r);
            bufP[r * 17 + kk] = pos[row * N1 + cc * 16 + kk];
            bufN[r * 17 + kk] = neg[row * N1 + cc * 16 + kk];
        }
        __syncthreads();
        // Dv: [vl][512 j], writes coalesced, reads from LDS transpose
        for (int idx = threadIdx.x; idx < 8192; idx += 256) {
            const int vl = idx >> 9, j = idx & 511;
            const int vlo = j >> 5, c = j & 15;
            const int m = (j >> 4) & 1;
            const float x = (m ? bufN : bufP)[(vlo * 16 + c) * 17 + vl];
            Dv[(size_t)cc * 8192 + idx] = m ? -x : x;
        }
        // Bv: 512 per chunk (bias column), tiny scattered read is fine
        for (int j = threadIdx.x; j < 512; j += 256) {
            const int vlo = j >> 5, c = j & 15;
            const int m = (j >> 4) & 1;
            const float* src = m ? neg : pos;
            const float x = src[(size_t)(cc * 256 + vlo * 16 + c) * N1 + V];
            Bv[(size_t)cc * 512 + j] = m ? -x : x;
        }
    }
}

// ---- fused main kernel: 32 rows, 16 waves, grid 256 ----------------------------
// Wave w: GEMM j-tiles t = 2w..2w+1 (both 16-row halves, acc[2][2]); chain owns
// rows 2w..2w+1. Per chunk: dump acc -> S, barrier, 16-step barrier-free in-wave
// chain interleaving chunk cc+1's bulk GEMM k-blocks, barrier, final k-block.
// mat=1 values live negated end-to-end: every reduce is max, upper = -red.
// R4: fb pipeline RETAINED but paid for in registers. Evidence (R1 spill-free
// at 64, R3 +8 regs -> 8 spill slots) says the arch-VGPR cap is 64 (unified
// file split 64 VGPR + 64 AGPR; rocprof reports the arch half). So the 16-reg
// po prefetch block is replaced by a 1-step-ahead 4-reg po window (2 scalar
// ds_read_u16/step, issued a full chain-step before use). Net live-window
// delta vs R1: -16 +4 +8(fb) = -4 -> no spill. Safety of po-ahead read:
// column vcur+1 is written only at step vl+1 (after the read in program
// order); other waves write only their own rows.
__global__ __launch_bounds__(NT, 4)
void shield_fused(const float* __restrict__ preds,
                  const bf16_t* __restrict__ Mhi,
                  const float* __restrict__ Dv, const float* __restrict__ Bv,
                  float* __restrict__ out)
{
    __shared__ bf16_t Phi[RB * PKS];   // 33,280 B
    __shared__ float  S[RB * SJP];     // 98,816 B  (total 132,096 -> 1 block/CU)

    const int tid  = threadIdx.x;
    const int b0   = blockIdx.x * RB;
    const int lane = tid & 63;
    const int w    = tid >> 6;          // 0..15
    const int cq   = lane & 15;
    const int q    = lane >> 4;
    const int rp0  = w * 2;             // chain rows 2w, 2w+1

    // ---- load preds -> Phi ----
    {
        const int r = tid >> 5, seg = tid & 31;
        const float* prow = preds + (size_t)(b0 + r) * V + seg * 16;
        #pragma unroll
        for (int k = 0; k < 16; k += 4) {
            const float4 p4 = *(const float4*)(prow + k);
            const int n = seg * 16 + k;
            Phi[r * PKS + n + 0] = (bf16_t)p4.x;
            Phi[r * PKS + n + 1] = (bf16_t)p4.y;
            Phi[r * PKS + n + 2] = (bf16_t)p4.z;
            Phi[r * PKS + n + 3] = (bf16_t)p4.w;
        }
    }

    int tJ[2], sct[2];
    #pragma unroll
    for (int tt = 0; tt < 2; ++tt) {
        tJ[tt]  = ((2 * w + tt) << 4) + cq;
        sct[tt] = 12 * (tJ[tt] >> 3) + (tJ[tt] & 7);   // padded S column
    }
    const int aoff0 = cq * PKS + 8 * q;
    const int aoff1 = (16 + cq) * PKS + 8 * q;

    // acc(0) = bias(0)
    f32x4 acc[2][2];
    #pragma unroll
    for (int tt = 0; tt < 2; ++tt) {
        const float b = Bv[tJ[tt]];
        acc[0][tt] = f32x4{b, b, b, b};
        acc[1][tt] = f32x4{b, b, b, b};
    }

    #pragma unroll 1
    for (int cc = 0; cc < NCHUNKS; ++cc) {
        const int v0 = cc * 16;
        const int  ccn  = cc + 1;
        const bool hasN = ccn < NCHUNKS;
        const int  nkbN = hasN ? ((ccn + 1) >> 1) : 0;
        const bf16_t* phN = Mhi + 16384ull * (size_t)((ccn * ccn) / 4)
                          + (size_t)lane * 8 + (size_t)(2 * w) * 512;

        // ---- dump acc(cc) -> S (padded columns) ----
        #pragma unroll
        for (int tt = 0; tt < 2; ++tt)
            #pragma unroll
            for (int reg = 0; reg < 4; ++reg) {
                S[(4 * q + reg) * SJP + sct[tt]]      = acc[0][tt][reg];
                S[(16 + 4 * q + reg) * SJP + sct[tt]] = acc[1][tt][reg];
            }
        __syncthreads();   // (A) S ready; prior Phi writes visible

        // ---- load s2: lane owns j = 8*lane..8*lane+7, rows 2w / 2w+1 ----
        // padded layout: group g at dword 12*g -> 8 consecutive lanes cover all
        // 32 banks exactly once per b128 (optimal 8 phases)
        f32x2 s2[8];
        {
            const float* sp = &S[rp0 * SJP + 12 * lane];
            const float4 a0 = *(const float4*)(sp);
            const float4 a1 = *(const float4*)(sp + 4);
            const float4 c0 = *(const float4*)(sp + SJP);
            const float4 c1 = *(const float4*)(sp + SJP + 4);
            s2[0] = f32x2{a0.x, c0.x}; s2[1] = f32x2{a0.y, c0.y};
            s2[2] = f32x2{a0.z, c0.z}; s2[3] = f32x2{a0.w, c0.w};
            s2[4] = f32x2{a1.x, c1.x}; s2[5] = f32x2{a1.y, c1.y};
            s2[6] = f32x2{a1.z, c1.z}; s2[7] = f32x2{a1.w, c1.w};
        }

        // ---- init acc(ccn) with bias ----
        if (hasN) {
            #pragma unroll
            for (int tt = 0; tt < 2; ++tt) {
                const float b = Bv[(ccn << 9) + tJ[tt]];
                acc[0][tt] = f32x4{b, b, b, b};
                acc[1][tt] = f32x4{b, b, b, b};
            }
        }

        // ---- pipeline prologue: fb k-block 0 of chunk ccn; po of step 0 ----
        bf16x8 fbn0, fbn1;
        if (hasN && nkbN > 1) {
            fbn0 = *(const bf16x8*)(phN);
            fbn1 = *(const bf16x8*)(phN + 512);
        }
        float poc[2];
        poc[0] = (float)Phi[rp0 * PKS + v0];
        poc[1] = (float)Phi[(rp0 + 1) * PKS + v0];

        // ---- 16-step serial chain + interleaved bulk GEMM of chunk ccn ----
        #pragma unroll
        for (int vl = 0; vl < KCH; ++vl) {
            const int vcur = v0 + vl;
            const bool doKb  = hasN && (vl < nkbN - 1);
            const bool doKbN = hasN && (vl + 1 < nkbN - 1);
            const bool doFin = hasN && (vl + 1 == nkbN - 1);  // final kb's fb

            // consume this step's fb; issue next step's (or the final
            // k-block's) fb NOW -> a full chain-step of global-latency cover.
            // Mhi is constant, so this never races the chain's Phi writes.
            const bf16x8 fb0 = fbn0, fb1 = fbn1;
            if (doKbN || doFin) {
                const int k0 = (vl + 1) * 32;
                const bf16_t* pb = phN + (size_t)k0 * 512;
                fbn0 = *(const bf16x8*)(pb);
                fbn1 = *(const bf16x8*)(pb + 512);
            }

            // po window: read NEXT step's column now (full step of LDS cover)
            float pon[2];
            if (vl + 1 < KCH) {
                pon[0] = (float)Phi[rp0 * PKS + vcur + 1];
                pon[1] = (float)Phi[(rp0 + 1) * PKS + vcur + 1];
            }

            // fa (LDS) issued at step top: ~100cy of in-step cover, and reads
            // only Phi cols k < 16*cc -- strictly older than any chain write
            bf16x8 fa0, fa1;
            if (doKb) {
                const int k0 = vl * 32;
                fa0 = *(const bf16x8*)(Phi + aoff0 + k0);
                fa1 = *(const bf16x8*)(Phi + aoff1 + k0);
            }

            // this step's dv (global, L1/L2-hot); consumed post-reduce
            float dv[8];
            {
                const float* dp = Dv + ((size_t)vcur << 9) + 8 * lane;
                const float4 d0 = *(const float4*)(dp);
                const float4 d1 = *(const float4*)(dp + 4);
                dv[0]=d0.x; dv[1]=d0.y; dv[2]=d0.z; dv[3]=d0.w;
                dv[4]=d1.x; dv[5]=d1.y; dv[6]=d1.z; dv[7]=d1.w;
            }

            // in-lane reduce 8 -> 1 per row (max3-fusable), xor-1 merge via DPP
            float red[2];
            #pragma unroll
            for (int r = 0; r < 2; ++r) {
                const float m0 = fmaxf(fmaxf(s2[0][r], s2[1][r]), s2[2][r]);
                const float m1 = fmaxf(fmaxf(s2[3][r], s2[4][r]), s2[5][r]);
                const float m2 = fmaxf(s2[6][r], s2[7][r]);
                const float mxr = fmaxf(fmaxf(m0, m1), m2);
                red[r] = dpp_xor1_max(mxr);
            }
            // broadcast from compile-time lanes via v_readlane (no DS op)
            float pc[2];
            #pragma unroll
            for (int r = 0; r < 2; ++r) {
                const float lw  = bcast_lane(red[r], 4 * vl);       // lower
                const float nup = bcast_lane(red[r], 4 * vl + 2);   // -upper
                pc[r] = fminf(fmaxf(poc[r], lw), -nup);
            }
            if (lane == 4 * vl) {
                Phi[rp0 * PKS + vcur]       = (bf16_t)pc[0];
                Phi[(rp0 + 1) * PKS + vcur] = (bf16_t)pc[1];
            }
            // rank-1 update (packed fp32 fma; Dv pre-scaled so no sign mul)
            const f32x2 pcv = {pc[0], pc[1]};
            #pragma unroll
            for (int jj = 0; jj < 8; ++jj) {
                const f32x2 dsp = {dv[jj], dv[jj]};
                s2[jj] = __builtin_elementwise_fma(dsp, pcv, s2[jj]);
            }

            if (doKb) {
                acc[0][0] = mfma16(fa0, fb0, acc[0][0]);
                acc[1][0] = mfma16(fa1, fb0, acc[1][0]);
                acc[0][1] = mfma16(fa0, fb1, acc[0][1]);
                acc[1][1] = mfma16(fa1, fb1, acc[1][1]);
            }

            // shift po window
            poc[0] = pon[0];
            poc[1] = pon[1];
        }

        __syncthreads();   // (D) fresh Phi columns visible; S safe to reuse

        // ---- final k-block of chunk ccn (zero-padded B -> exact no-ops) ----
        // fb was prefetched during the chain (doFin) except when nkbN==1.
        if (hasN) {
            const int k0 = (nkbN - 1) * 32;
            bf16x8 fb0f = fbn0, fb1f = fbn1;
            if (nkbN == 1) {
                const bf16_t* pb = phN + (size_t)k0 * 512;
                fb0f = *(const bf16x8*)(pb);
                fb1f = *(const bf16x8*)(pb + 512);
            }
            const bf16x8 fa0 = *(const bf16x8*)(Phi + aoff0 + k0);
            const bf16x8 fa1 = *(const bf16x8*)(Phi + aoff1 + k0);
            acc[0][0] = mfma16(fa0, fb0f, acc[0][0]);
            acc[1][0] = mfma16(fa1, fb0f, acc[1][0]);
            acc[0][1] = mfma16(fa0, fb1f, acc[0][1]);
            acc[1][1] = mfma16(fa1, fb1f, acc[1][1]);
        }
    }

    // ---- epilogue ----
    {
        const int r = tid >> 5, seg = tid & 31;
        float* orow = out + (size_t)(b0 + r) * V + seg * 16;
        #pragma unroll
        for (int k = 0; k < 16; k += 4) {
            const int n = seg * 16 + k;
            float4 o;
            o.x = (float)Phi[r * PKS + n + 0];
            o.y = (float)Phi[r * PKS + n + 1];
            o.z = (float)Phi[r * PKS + n + 2];
            o.w = (float)Phi[r * PKS + n + 3];
            *(float4*)(orow + k) = o;
        }
    }
}

extern "C" void kernel_launch(void* const* d_in, const int* in_sizes, int n_in,
                              void* d_out, int out_size, void* d_ws, size_t ws_size,
                              hipStream_t stream) {
    const float* preds = (const float*)d_in[0];
    const float* pos   = (const float*)d_in[1];
    const float* neg   = (const float*)d_in[2];
    float* o = (float*)d_out;
    char* base = (char*)d_ws;
    bf16_t* Mhi = (bf16_t*)base;
    float*  Dv  = (float*)(base + DV_OFF);
    float*  Bv  = (float*)(base + BV_OFF);
    repack_all<<<dim3(528), 256, 0, stream>>>(pos, neg, Mhi, Dv, Bv);
    shield_fused<<<dim3(BATCH / RB), NT, 0, stream>>>(preds, Mhi, Dv, Bv, o);
}

// Round 5
// 380.030 us; speedup vs baseline: 1.5372x; 1.0609x over previous
//
#include <hip/hip_runtime.h>

#define BATCH 8192
#define V 512
#define N1 513
#define KCH 16
#define NCHUNKS 32
#define RB 32            // rows per block -> grid 256
#define NT 1024          // 16 waves in ONE block -> 4 waves/SIMD guaranteed
#define PKS 520          // Phi row stride (bf16 elems)
#define SJP 772          // padded S row stride (dwords): col j at 12*(j>>3)+(j&7)

typedef __bf16 bf16_t;
typedef bf16_t bf16x8 __attribute__((ext_vector_type(8)));
typedef float f32x4 __attribute__((ext_vector_type(4)));
typedef float f32x2 __attribute__((ext_vector_type(2)));

// workspace: Mhi (fragment-linear triangular pack, mat=1 tiles PRE-NEGATED),
// Dv (fp32, pre-scaled by mat sign), Bv (fp32, pre-negated mat=1).
//   chunk cc in 1..31: nkb = ceil(cc/2) k-blocks of 32 (zero-pad past 16*cc);
//   base elems = 16384*floor(cc^2/4); elem = base + (kb*32 + t)*512 + lane*8 + jj
//   with t = 2*vl + mat, lane = c + 16*q, k = kb*32 + 8*q + jj.
// Dv: [cc][vl][512 j], j = 32*vlo + 16*mat + c. Bv: [cc][512 j].
#define EPP 4194304ull
#define DV_OFF (EPP * 2ull)
#define BV_OFF (DV_OFF + 1048576ull)

__device__ __forceinline__ f32x4 mfma16(bf16x8 a, bf16x8 b, f32x4 c) {
    return __builtin_amdgcn_mfma_f32_16x16x32_bf16(a, b, c, 0, 0, 0);
}

__device__ __forceinline__ float bcast_lane(float x, int l) {
    return __int_as_float(__builtin_amdgcn_readlane(__float_as_int(x), l));
}

__device__ __forceinline__ float dpp_xor1_max(float x) {
    const int xi = __float_as_int(x);
    // quad_perm [1,0,3,2] = 0xB1 -> swap xor-1 neighbours, no DS op
    const float o = __int_as_float(
        __builtin_amdgcn_update_dpp(xi, xi, 0xB1, 0xF, 0xF, false));
    return fmaxf(x, o);
}

// ---- unified repack, R5: 1024 threads/block (16 waves/CU -> real TLP for a
// pure-memory kernel; the 256-thread version ran at ~4 waves/CU and was
// latency-bound at ~10% of HBM). Mhi output vectorized to bf16x8 stores via
// 16B-aligned LDS reads (row stride 36 dwords). Blocks 0..495 pack Mhi;
// 496..527 pack Dv/Bv (stride-17 views alias the same LDS buffer). ----------
__global__ __launch_bounds__(1024)
void repack_all(const float* __restrict__ pos, const float* __restrict__ neg,
                bf16_t* __restrict__ Mhi, float* __restrict__ Dv,
                float* __restrict__ Bv)
{
    __shared__ float sb[2 * 256 * 36];   // 73,728 B
    const int bx  = blockIdx.x;
    const int tid = threadIdx.x;
    if (bx < 496) {
        const int cc  = (bx >> 4) + 1;       // 1..31
        const int kb  = bx & 15;
        const int nkb = (cc + 1) >> 1;
        if (kb >= nkb) return;
        const int klen = 16 * cc;
        // stage tile rows [cc*256,+256) x cols [kb*32,+32): coalesced (128B
        // per row-segment), pre-signed, zero-padded past klen
        for (int idx = tid; idx < 8192; idx += 1024) {
            const int r = idx >> 5, k32 = idx & 31;
            const int k = kb * 32 + k32;
            const size_t row = (size_t)cc * 256 + r;
            float xp = 0.0f, xn = 0.0f;
            if (k < klen) {
                xp = pos[row * N1 + k];
                xn = -neg[row * N1 + k];     // pre-negate mat=1
            }
            sb[r * 36 + k32]            = xp;
            sb[256 * 36 + r * 36 + k32] = xn;
        }
        __syncthreads();
        const size_t base = 16384ull * (size_t)((cc * cc) / 4) + (size_t)kb * 16384ull;
        // 8 output elems per thread: LDS reads 16B-aligned (36r+8q ≡ 0 mod 4),
        // one bf16x8 (16B) coalesced global store
        for (int e8 = tid; e8 < 2048; e8 += 1024) {
            const int t = e8 >> 6, s = e8 & 63;
            const int c = s & 15, q = s >> 4;
            const int vloc = t >> 1, m = t & 1;
            const float* sp = &sb[m * 256 * 36 + (vloc * 16 + c) * 36 + 8 * q];
            bf16x8 o;
            #pragma unroll
            for (int jj = 0; jj < 8; ++jj) o[jj] = (bf16_t)sp[jj];
            *(bf16x8*)(Mhi + base + (size_t)e8 * 8) = o;
        }
    } else {
        const int cc = bx - 496;             // 0..31, one block per chunk
        float* bufP = sb;                    // stride-17 views
        float* bufN = sb + 256 * 17;
        // stage rows [cc*256, cc*256+256) cols [cc*16, cc*16+16), coalesced
        for (int idx = tid; idx < 4096; idx += 1024) {
            const int r = idx >> 4, kk = idx & 15;
            const size_t row = (size_t)(cc * 256 + r);
            bufP[r * 17 + kk] = pos[row * N1 + cc * 16 + kk];
            bufN[r * 17 + kk] = neg[row * N1 + cc * 16 + kk];
        }
        __syncthreads();
        // Dv: [vl][512 j], writes coalesced, reads from LDS transpose
        for (int idx = tid; idx < 8192; idx += 1024) {
            const int vl = idx >> 9, j = idx & 511;
            const int vlo = j >> 5, c = j & 15;
            const int m = (j >> 4) & 1;
            const float x = (m ? bufN : bufP)[(vlo * 16 + c) * 17 + vl];
            Dv[(size_t)cc * 8192 + idx] = m ? -x : x;
        }
        // Bv: 512 per chunk (bias column), tiny scattered read is fine
        for (int j = tid; j < 512; j += 1024) {
            const int vlo = j >> 5, c = j & 15;
            const int m = (j >> 4) & 1;
            const float* src = m ? neg : pos;
            const float x = src[(size_t)(cc * 256 + vlo * 16 + c) * N1 + V];
            Bv[(size_t)cc * 512 + j] = m ? -x : x;
        }
    }
}

// ---- fused main kernel: 32 rows, 16 waves, grid 256 ----------------------------
// Wave w: GEMM j-tiles t = 2w..2w+1 (both 16-row halves, acc[2][2]); chain owns
// rows 2w..2w+1. Per chunk: dump acc -> S, barrier, 16-step barrier-free in-wave
// chain interleaving chunk cc+1's bulk GEMM k-blocks, barrier, final k-block.
// mat=1 values live negated end-to-end: every reduce is max, upper = -red.
// R5: EXACT R1 code (measured 325us, zero spill). R2/R3/R4 established that at
// 16 waves/block the arch-VGPR cap is 64/wave (pool ~256/SIMD at 4 waves/SIMD;
// unified-file AGPR half holds the MFMA accumulators): every widened live
// window (full pipeline, fb-only +8, fb+po-window) spilled to scratch
// (WRITE_SIZE 685/25.6/21.5 MB) and regressed. Do not add cross-step state.
__global__ __launch_bounds__(NT, 4)
void shield_fused(const float* __restrict__ preds,
                  const bf16_t* __restrict__ Mhi,
                  const float* __restrict__ Dv, const float* __restrict__ Bv,
                  float* __restrict__ out)
{
    __shared__ bf16_t Phi[RB * PKS];   // 33,280 B
    __shared__ float  S[RB * SJP];     // 98,816 B  (total 132,096 -> 1 block/CU)

    const int tid  = threadIdx.x;
    const int b0   = blockIdx.x * RB;
    const int lane = tid & 63;
    const int w    = tid >> 6;          // 0..15
    const int cq   = lane & 15;
    const int q    = lane >> 4;
    const int rp0  = w * 2;             // chain rows 2w, 2w+1

    // ---- load preds -> Phi ----
    {
        const int r = tid >> 5, seg = tid & 31;
        const float* prow = preds + (size_t)(b0 + r) * V + seg * 16;
        #pragma unroll
        for (int k = 0; k < 16; k += 4) {
            const float4 p4 = *(const float4*)(prow + k);
            const int n = seg * 16 + k;
            Phi[r * PKS + n + 0] = (bf16_t)p4.x;
            Phi[r * PKS + n + 1] = (bf16_t)p4.y;
            Phi[r * PKS + n + 2] = (bf16_t)p4.z;
            Phi[r * PKS + n + 3] = (bf16_t)p4.w;
        }
    }

    int tJ[2], sct[2];
    #pragma unroll
    for (int tt = 0; tt < 2; ++tt) {
        tJ[tt]  = ((2 * w + tt) << 4) + cq;
        sct[tt] = 12 * (tJ[tt] >> 3) + (tJ[tt] & 7);   // padded S column
    }
    const int aoff0 = cq * PKS + 8 * q;
    const int aoff1 = (16 + cq) * PKS + 8 * q;

    // acc(0) = bias(0)
    f32x4 acc[2][2];
    #pragma unroll
    for (int tt = 0; tt < 2; ++tt) {
        const float b = Bv[tJ[tt]];
        acc[0][tt] = f32x4{b, b, b, b};
        acc[1][tt] = f32x4{b, b, b, b};
    }

    #pragma unroll 1
    for (int cc = 0; cc < NCHUNKS; ++cc) {
        const int v0 = cc * 16;
        const int  ccn  = cc + 1;
        const bool hasN = ccn < NCHUNKS;
        const int  nkbN = hasN ? ((ccn + 1) >> 1) : 0;
        const bf16_t* phN = Mhi + 16384ull * (size_t)((ccn * ccn) / 4)
                          + (size_t)lane * 8 + (size_t)(2 * w) * 512;

        // ---- dump acc(cc) -> S (padded columns) ----
        #pragma unroll
        for (int tt = 0; tt < 2; ++tt)
            #pragma unroll
            for (int reg = 0; reg < 4; ++reg) {
                S[(4 * q + reg) * SJP + sct[tt]]      = acc[0][tt][reg];
                S[(16 + 4 * q + reg) * SJP + sct[tt]] = acc[1][tt][reg];
            }
        __syncthreads();   // (A) S ready; prior Phi writes visible

        // ---- load s2: lane owns j = 8*lane..8*lane+7, rows 2w / 2w+1 ----
        // padded layout: group g at dword 12*g -> 8 consecutive lanes cover all
        // 32 banks exactly once per b128 (optimal 8 phases)
        f32x2 s2[8];
        {
            const float* sp = &S[rp0 * SJP + 12 * lane];
            const float4 a0 = *(const float4*)(sp);
            const float4 a1 = *(const float4*)(sp + 4);
            const float4 c0 = *(const float4*)(sp + SJP);
            const float4 c1 = *(const float4*)(sp + SJP + 4);
            s2[0] = f32x2{a0.x, c0.x}; s2[1] = f32x2{a0.y, c0.y};
            s2[2] = f32x2{a0.z, c0.z}; s2[3] = f32x2{a0.w, c0.w};
            s2[4] = f32x2{a1.x, c1.x}; s2[5] = f32x2{a1.y, c1.y};
            s2[6] = f32x2{a1.z, c1.z}; s2[7] = f32x2{a1.w, c1.w};
        }

        // ---- prefetch this chunk's po values (cols v0..v0+15, both rows) ----
        // valid: these cols are only corrected at their own step, and each
        // step reads strictly its own column
        const bf16x8 poA0 = *(const bf16x8*)(Phi + rp0 * PKS + v0);
        const bf16x8 poA1 = *(const bf16x8*)(Phi + rp0 * PKS + v0 + 8);
        const bf16x8 poB0 = *(const bf16x8*)(Phi + (rp0 + 1) * PKS + v0);
        const bf16x8 poB1 = *(const bf16x8*)(Phi + (rp0 + 1) * PKS + v0 + 8);

        // ---- init acc(ccn) with bias ----
        if (hasN) {
            #pragma unroll
            for (int tt = 0; tt < 2; ++tt) {
                const float b = Bv[(ccn << 9) + tJ[tt]];
                acc[0][tt] = f32x4{b, b, b, b};
                acc[1][tt] = f32x4{b, b, b, b};
            }
        }

        // ---- 16-step serial chain + interleaved bulk GEMM of chunk ccn ----
        #pragma unroll
        for (int vl = 0; vl < KCH; ++vl) {
            const int vcur = v0 + vl;
            const bool doKb = hasN && (vl < nkbN - 1);

            bf16x8 fa0, fa1, fb0, fb1;
            if (doKb) {
                const int k0 = vl * 32;
                fa0 = *(const bf16x8*)(Phi + aoff0 + k0);
                fa1 = *(const bf16x8*)(Phi + aoff1 + k0);
                const bf16_t* pb = phN + (size_t)k0 * 512;
                fb0 = *(const bf16x8*)(pb);
                fb1 = *(const bf16x8*)(pb + 512);
            }

            // this step's dv (global, L2-hot); consumed post-reduce
            float dv[8];
            {
                const float* dp = Dv + ((size_t)vcur << 9) + 8 * lane;
                const float4 d0 = *(const float4*)(dp);
                const float4 d1 = *(const float4*)(dp + 4);
                dv[0]=d0.x; dv[1]=d0.y; dv[2]=d0.z; dv[3]=d0.w;
                dv[4]=d1.x; dv[5]=d1.y; dv[6]=d1.z; dv[7]=d1.w;
            }
            const float po_[2] = {
                (float)(vl < 8 ? poA0[vl & 7] : poA1[vl & 7]),
                (float)(vl < 8 ? poB0[vl & 7] : poB1[vl & 7])
            };

            // in-lane reduce 8 -> 1 per row (max3-fusable), xor-1 merge via DPP
            float red[2];
            #pragma unroll
            for (int r = 0; r < 2; ++r) {
                const float m0 = fmaxf(fmaxf(s2[0][r], s2[1][r]), s2[2][r]);
                const float m1 = fmaxf(fmaxf(s2[3][r], s2[4][r]), s2[5][r]);
                const float m2 = fmaxf(s2[6][r], s2[7][r]);
                const float mxr = fmaxf(fmaxf(m0, m1), m2);
                red[r] = dpp_xor1_max(mxr);
            }
            // broadcast from compile-time lanes via v_readlane (no DS op)
            float pc[2];
            #pragma unroll
            for (int r = 0; r < 2; ++r) {
                const float lw  = bcast_lane(red[r], 4 * vl);       // lower
                const float nup = bcast_lane(red[r], 4 * vl + 2);   // -upper
                pc[r] = fminf(fmaxf(po_[r], lw), -nup);
            }
            if (lane == 4 * vl) {
                Phi[rp0 * PKS + vcur]       = (bf16_t)pc[0];
                Phi[(rp0 + 1) * PKS + vcur] = (bf16_t)pc[1];
            }
            // rank-1 update (packed fp32 fma; Dv pre-scaled so no sign mul)
            const f32x2 pcv = {pc[0], pc[1]};
            #pragma unroll
            for (int jj = 0; jj < 8; ++jj) {
                const f32x2 dsp = {dv[jj], dv[jj]};
                s2[jj] = __builtin_elementwise_fma(dsp, pcv, s2[jj]);
            }

            if (doKb) {
                acc[0][0] = mfma16(fa0, fb0, acc[0][0]);
                acc[1][0] = mfma16(fa1, fb0, acc[1][0]);
                acc[0][1] = mfma16(fa0, fb1, acc[0][1]);
                acc[1][1] = mfma16(fa1, fb1, acc[1][1]);
            }
        }

        __syncthreads();   // (D) fresh Phi columns visible; S safe to reuse

        // ---- final k-block of chunk ccn (zero-padded B -> exact no-ops) ----
        if (hasN) {
            const int k0 = (nkbN - 1) * 32;
            const bf16x8 fa0 = *(const bf16x8*)(Phi + aoff0 + k0);
            const bf16x8 fa1 = *(const bf16x8*)(Phi + aoff1 + k0);
            const bf16_t* pb = phN + (size_t)k0 * 512;
            const bf16x8 fb0 = *(const bf16x8*)(pb);
            const bf16x8 fb1 = *(const bf16x8*)(pb + 512);
            acc[0][0] = mfma16(fa0, fb0, acc[0][0]);
            acc[1][0] = mfma16(fa1, fb0, acc[1][0]);
            acc[0][1] = mfma16(fa0, fb1, acc[0][1]);
            acc[1][1] = mfma16(fa1, fb1, acc[1][1]);
        }
    }

    // ---- epilogue ----
    {
        const int r = tid >> 5, seg = tid & 31;
        float* orow = out + (size_t)(b0 + r) * V + seg * 16;
        #pragma unroll
        for (int k = 0; k < 16; k += 4) {
            const int n = seg * 16 + k;
            float4 o;
            o.x = (float)Phi[r * PKS + n + 0];
            o.y = (float)Phi[r * PKS + n + 1];
            o.z = (float)Phi[r * PKS + n + 2];
            o.w = (float)Phi[r * PKS + n + 3];
            *(float4*)(orow + k) = o;
        }
    }
}

extern "C" void kernel_launch(void* const* d_in, const int* in_sizes, int n_in,
                              void* d_out, int out_size, void* d_ws, size_t ws_size,
                              hipStream_t stream) {
    const float* preds = (const float*)d_in[0];
    const float* pos   = (const float*)d_in[1];
    const float* neg   = (const float*)d_in[2];
    float* o = (float*)d_out;
    char* base = (char*)d_ws;
    bf16_t* Mhi = (bf16_t*)base;
    float*  Dv  = (float*)(base + DV_OFF);
    float*  Bv  = (float*)(base + BV_OFF);
    repack_all<<<dim3(528), 1024, 0, stream>>>(pos, neg, Mhi, Dv, Bv);
    shield_fused<<<dim3(BATCH / RB), NT, 0, stream>>>(preds, Mhi, Dv, Bv, o);
}